// Round 12
// baseline (49.289 us; speedup 1.0000x reference)
//
#include <hip/hip_runtime.h>
#include <hip/hip_bf16.h>
#include <hip/hip_fp16.h>

// Self-attention: B=4, N=4096 (64x64 spatial), C=256, D=32.
//   proj_kernel  : MFMA GEMM (validated ~2.5us). k,q row-major [B*N][32] f16
//                  (q pre-scaled by log2e); v packed per-consumer-lane:
//                  vT3[ntile][lane][16B] = {V[d=q][4k], V[d=16+q][4k]}, lane=(g<<4)|q.
//   attn_partial : split-K flash attention. grid 256 = 16 qu x 4 b x 4 ks.
//                  Block = 256 q-rows x 1024 k. K/V staged to LDS via
//                  global_load_lds (width 16), shared by all 8 waves; wave owns
//                  2 q-tiles. Partials (m, ssum, accT fp32) -> workspace.
//   attn_combine : exact softmax merge of 4 k-split partials + MFMA Wo-epilogue
//                  (Wo^T in LDS) + gamma*.. + x residual.

#define BB 4
#define NN 4096
#define CC 256
#define DD 32
#define LOG2E 1.44269504088896340736f
#define THR2 11.0f
#define NROW (BB * NN)      // 16384
#define KSPLIT 4
#define NCH 16              // chunks of 64 k per block (4 k-tiles each)

typedef _Float16 half_t;
typedef _Float16 half2_t __attribute__((ext_vector_type(2)));
typedef _Float16 half4_t __attribute__((ext_vector_type(4)));
typedef _Float16 half8_t __attribute__((ext_vector_type(8)));
typedef float f32x4 __attribute__((ext_vector_type(4)));

#define MFMA_QK(a, b, c) __builtin_amdgcn_mfma_f32_16x16x32_f16(a, b, c, 0, 0, 0)
#define MFMA_PV(a, b, c) __builtin_amdgcn_mfma_f32_16x16x16f16(a, b, c, 0, 0, 0)

static __device__ inline float fexp2(float x) {
#if __has_builtin(__builtin_amdgcn_exp2f)
    return __builtin_amdgcn_exp2f(x);
#else
    return exp2f(x);
#endif
}

// global->LDS DMA, 16B per lane. LDS dest = (wave-uniform base) + lane*16;
// global src is per-lane.
static __device__ __forceinline__ void stage16(const void* g, void* l) {
    __builtin_amdgcn_global_load_lds(
        (const __attribute__((address_space(1))) void*)g,
        (__attribute__((address_space(3))) void*)l, 16, 0, 0);
}

// ---------------- Kernel 1: fused QKV projection (MFMA) ----------------
// grid 256 blocks x 512 threads (8 waves); block = 64 rows of x.
__global__ __launch_bounds__(512) void proj_kernel(
    const float* __restrict__ x,
    const float* __restrict__ Wk, const float* __restrict__ bk,
    const float* __restrict__ Wq, const float* __restrict__ bq,
    const float* __restrict__ Wv, const float* __restrict__ bv,
    half_t* __restrict__ k_ws, half_t* __restrict__ q_ws, half_t* __restrict__ vT3)
{
    __shared__ half_t xs16[64][264];  // x tile f16 (rows 16B-aligned)
    __shared__ half_t Wt[96][264];    // [Wk|Wq|Wv]^T : Wt[wcol][kdim]

    const int t = threadIdx.x;
    const int xcd = blockIdx.x & 7, slot = blockIdx.x >> 3;
    const int bb = xcd >> 1;                      // batch 0..3
    const int c64 = (slot << 1) | (xcd & 1);      // chunk 0..63
    const int row0 = bb * NN + c64 * 64;

    // stage x tile [64][256] fp32 -> f16
    const float4* x4 = reinterpret_cast<const float4*>(x) + (size_t)row0 * 64;
    for (int idx = t; idx < 64 * 64; idx += 512) {
        int r = idx >> 6, c4 = idx & 63;
        float4 v = x4[r * 64 + c4];
        half4_t h;
        h[0] = (half_t)v.x; h[1] = (half_t)v.y; h[2] = (half_t)v.z; h[3] = (half_t)v.w;
        *reinterpret_cast<half4_t*>(&xs16[r][c4 * 4]) = h;
    }

    // stage W^T (q columns pre-scaled by log2e)
    for (int idx = t; idx < 3072; idx += 512) {
        int cp = idx & 127;           // c-pair
        int rest = idx >> 7;          // 0..23
        int d4 = (rest & 7) * 4;
        int mat = rest >> 3;          // 0:k 1:q 2:v
        const float* Wm = (mat == 0) ? Wk : ((mat == 1) ? Wq : Wv);
        const float sc = (mat == 1) ? LOG2E : 1.0f;
        float4 w0 = *reinterpret_cast<const float4*>(Wm + (2 * cp) * DD + d4);
        float4 w1 = *reinterpret_cast<const float4*>(Wm + (2 * cp + 1) * DD + d4);
        int rbase = mat * 32 + d4;
        half2_t h;
        h[0] = (half_t)(w0.x * sc); h[1] = (half_t)(w1.x * sc);
        *reinterpret_cast<half2_t*>(&Wt[rbase + 0][2 * cp]) = h;
        h[0] = (half_t)(w0.y * sc); h[1] = (half_t)(w1.y * sc);
        *reinterpret_cast<half2_t*>(&Wt[rbase + 1][2 * cp]) = h;
        h[0] = (half_t)(w0.z * sc); h[1] = (half_t)(w1.z * sc);
        *reinterpret_cast<half2_t*>(&Wt[rbase + 2][2 * cp]) = h;
        h[0] = (half_t)(w0.w * sc); h[1] = (half_t)(w1.w * sc);
        *reinterpret_cast<half2_t*>(&Wt[rbase + 3][2 * cp]) = h;
    }
    __syncthreads();

    const int w = t >> 6, lane = t & 63;
    const int c = lane & 15, g = lane >> 4;
    const int rt = w >> 1;            // row tile 0..3
    const int ct0 = (w & 1) * 3;      // col tiles ct0..ct0+2

    f32x4 acc[3];
#pragma unroll
    for (int j = 0; j < 3; ++j) acc[j] = (f32x4){0.f, 0.f, 0.f, 0.f};

#pragma unroll
    for (int kk = 0; kk < 8; ++kk) {
        const int k0 = kk * 32 + g * 8;
        half8_t bfrag = *reinterpret_cast<const half8_t*>(&xs16[rt * 16 + c][k0]);
#pragma unroll
        for (int j = 0; j < 3; ++j) {
            half8_t afrag = *reinterpret_cast<const half8_t*>(&Wt[(ct0 + j) * 16 + c][k0]);
            acc[j] = MFMA_QK(afrag, bfrag, acc[j]);
        }
    }

    // store: lane holds C[xrow = rt*16+c][wcol = ct*16+4g+i]
    const int grow = row0 + rt * 16 + c;
#pragma unroll
    for (int j = 0; j < 3; ++j) {
        const int ct = ct0 + j;
        const int mat = ct >> 1;           // 0:k 1:q 2:v
        const float* bm = (mat == 0) ? bk : ((mat == 1) ? bq : bv);
        float4 bb4 = *reinterpret_cast<const float4*>(bm + (ct & 1) * 16 + g * 4);
        if (mat < 2) {
            const float bsc = (mat == 1) ? LOG2E : 1.0f;
            half_t* dst = (mat == 0) ? k_ws : q_ws;
            half4_t h;
            h[0] = (half_t)(acc[j][0] + bb4.x * bsc);
            h[1] = (half_t)(acc[j][1] + bb4.y * bsc);
            h[2] = (half_t)(acc[j][2] + bb4.z * bsc);
            h[3] = (half_t)(acc[j][3] + bb4.w * bsc);
            *reinterpret_cast<half4_t*>(dst + (size_t)grow * DD + (ct & 1) * 16 + g * 4) = h;
        } else {
            // vT3 packed: tile = grow>>4, kk' = grow&15 == c.
            // half index for (d, kk'): l = (kk'>>2)*16 + (d&15); h = l*8 + (d>=16?4:0) + (kk'&3)
            const size_t tbase = (size_t)(grow >> 4) * 512;
            const int d0 = (ct & 1) * 16 + g * 4;
            float bbi[4] = {bb4.x, bb4.y, bb4.z, bb4.w};
#pragma unroll
            for (int i = 0; i < 4; ++i) {
                int d = d0 + i;
                int l = ((c >> 2) << 4) | (d & 15);
                int h = l * 8 + ((d >> 4) << 2) + (c & 3);
                vT3[tbase + h] = (half_t)(acc[j][i] + bbi[i]);
            }
        }
    }
}

// ---------------- Kernel 2: split-K flash attention partial ----------------
// grid 256 blocks (qu*16 + b*4 + ks) x 512 threads (8 waves).
// Block: 256 q-rows (q-unit qu of batch b) x k in [ks*1024, (ks+1)*1024).
// Wave w owns q-tiles {2w, 2w+1}. K/V staged to LDS per 64-k chunk, double-buffered.
__global__ __launch_bounds__(512) void attn_partial(
    const half_t* __restrict__ k_ws, const half_t* __restrict__ q_ws,
    const half_t* __restrict__ vT3,
    float* __restrict__ pm, float* __restrict__ ps, float* __restrict__ pO)
{
    __shared__ half_t kbuf[2][4][512];   // 8 KB: [buf][ktile][lane-major 16B frags]
    __shared__ half_t vbuf[2][4][512];   // 8 KB

    const int tid = threadIdx.x;
    const int w = tid >> 6, lane = tid & 63;
    const int q = lane & 15, g = lane >> 4;
    const int qu = blockIdx.x >> 4;
    const int b = (blockIdx.x >> 2) & 3;
    const int ks = blockIdx.x & 3;
    const int r0 = b * NN + qu * 256;

    // Q fragments for this wave's two q-tiles (pre-scaled by log2e)
    half8_t qf0 = *reinterpret_cast<const half8_t*>(
        q_ws + (size_t)(r0 + (2 * w + 0) * 16 + q) * DD + g * 8);
    half8_t qf1 = *reinterpret_cast<const half8_t*>(
        q_ws + (size_t)(r0 + (2 * w + 1) * 16 + q) * DD + g * 8);

    float m[2] = {-3.0e38f, -3.0e38f}, ssum[2] = {0.f, 0.f};
    f32x4 accd0[2], accd1[2];
#pragma unroll
    for (int j = 0; j < 2; ++j) {
        accd0[j] = (f32x4){0.f, 0.f, 0.f, 0.f};
        accd1[j] = (f32x4){0.f, 0.f, 0.f, 0.f};
    }

    const int ktile0 = b * 256 + ks * 64;   // global k-tile base for this block
    const char* kb = (const char*)k_ws;
    const char* vb = (const char*)vT3;
    // K per-lane permuted source offset within a tile (so LDS lane*16 = lane's fragment)
    const int ksrc_off = q * 64 + g * 16;

    // prologue: stage chunk 0 into buf 0 (wave w<4: K tile w; w>=4: V tile w-4)
    {
        const size_t nt = (size_t)(ktile0 + (w & 3)) * 1024;
        if (w < 4) stage16(kb + nt + ksrc_off, &kbuf[0][w][0]);
        else       stage16(vb + nt + lane * 16, &vbuf[0][w - 4][0]);
    }

    for (int ch = 0; ch < NCH; ++ch) {
        __syncthreads();   // drains staging of chunk ch; fences reads of buf^1
        const int cb = ch & 1;
        if (ch + 1 < NCH) {
            const size_t nt = (size_t)(ktile0 + (ch + 1) * 4 + (w & 3)) * 1024;
            if (w < 4) stage16(kb + nt + ksrc_off, &kbuf[cb ^ 1][w][0]);
            else       stage16(vb + nt + lane * 16, &vbuf[cb ^ 1][w - 4][0]);
        }

#pragma unroll
        for (int tile = 0; tile < 4; ++tile) {
            half8_t kf = *reinterpret_cast<const half8_t*>(&kbuf[cb][tile][lane * 8]);
            half8_t vv = *reinterpret_cast<const half8_t*>(&vbuf[cb][tile][lane * 8]);

            f32x4 z = {0.f, 0.f, 0.f, 0.f};
            f32x4 s0 = MFMA_QK(kf, qf0, z);
            f32x4 s1 = MFMA_QK(kf, qf1, z);

            float t0 = fmaxf(fmaxf(s0[0], s0[1]), fmaxf(s0[2], s0[3]));
            float t1 = fmaxf(fmaxf(s1[0], s1[1]), fmaxf(s1[2], s1[3]));
            bool need = (t0 > m[0] + THR2) || (t1 > m[1] + THR2);
            if (__any(need)) {
                float r0m = fmaxf(t0, __shfl_xor(t0, 16));
                r0m = fmaxf(r0m, __shfl_xor(r0m, 32));
                float r1m = fmaxf(t1, __shfl_xor(t1, 16));
                r1m = fmaxf(r1m, __shfl_xor(r1m, 32));
                float mn0 = fmaxf(m[0], r0m), mn1 = fmaxf(m[1], r1m);
                float sc0 = fexp2(m[0] - mn0), sc1 = fexp2(m[1] - mn1);
                ssum[0] *= sc0; ssum[1] *= sc1;
                accd0[0] *= sc0; accd1[0] *= sc0;
                accd0[1] *= sc1; accd1[1] *= sc1;
                m[0] = mn0; m[1] = mn1;
            }

            float p00 = fexp2(s0[0] - m[0]), p01 = fexp2(s0[1] - m[0]);
            float p02 = fexp2(s0[2] - m[0]), p03 = fexp2(s0[3] - m[0]);
            float p10 = fexp2(s1[0] - m[1]), p11 = fexp2(s1[1] - m[1]);
            float p12 = fexp2(s1[2] - m[1]), p13 = fexp2(s1[3] - m[1]);
            ssum[0] += (p00 + p01) + (p02 + p03);
            ssum[1] += (p10 + p11) + (p12 + p13);

            half4_t pf0, pf1;
            pf0[0] = (half_t)p00; pf0[1] = (half_t)p01; pf0[2] = (half_t)p02; pf0[3] = (half_t)p03;
            pf1[0] = (half_t)p10; pf1[1] = (half_t)p11; pf1[2] = (half_t)p12; pf1[3] = (half_t)p13;

            half4_t va0 = __builtin_shufflevector(vv, vv, 0, 1, 2, 3);
            half4_t va1 = __builtin_shufflevector(vv, vv, 4, 5, 6, 7);

            accd0[0] = MFMA_PV(va0, pf0, accd0[0]);
            accd1[0] = MFMA_PV(va1, pf0, accd1[0]);
            accd0[1] = MFMA_PV(va0, pf1, accd0[1]);
            accd1[1] = MFMA_PV(va1, pf1, accd1[1]);
        }
    }

    // fold lane-local ssum to row sums
#pragma unroll
    for (int j = 0; j < 2; ++j) {
        ssum[j] += __shfl_xor(ssum[j], 16);
        ssum[j] += __shfl_xor(ssum[j], 32);
    }

    // write partials: pm/ps per row; pO[(ks*NROW + r)*32 + d]
#pragma unroll
    for (int j = 0; j < 2; ++j) {
        const int r = r0 + (2 * w + j) * 16 + q;
        if (lane < 16) {
            pm[(size_t)ks * NROW + r0 + (2 * w + j) * 16 + lane] = m[j];
            ps[(size_t)ks * NROW + r0 + (2 * w + j) * 16 + lane] = ssum[j];
        }
        float* po = pO + ((size_t)ks * NROW + r) * 32;
        *reinterpret_cast<f32x4*>(po + g * 4) = accd0[j];
        *reinterpret_cast<f32x4*>(po + 16 + g * 4) = accd1[j];
    }
}

// ---------------- Kernel 3: combine + output projection ----------------
// grid 256 blocks (b*64+qb) x 512 threads. Block = 64 q-rows.
__global__ __launch_bounds__(512) void attn_combine(
    const float* __restrict__ pm, const float* __restrict__ ps,
    const float* __restrict__ pO,
    const float* __restrict__ x, const float* __restrict__ Wo,
    const float* __restrict__ bo, const float* __restrict__ gamma,
    float* __restrict__ out)
{
    __shared__ half_t feat_h[64 * 40];    // 5 KB
    __shared__ half_t woT[256 * 40];      // 20 KB Wo^T f16: woT[c*40+d]

    const int tid = threadIdx.x;
    const int b = blockIdx.x >> 6, qb = blockIdx.x & 63;
    const int q0 = qb * 64;
    const int r0 = b * NN + q0;

    // stage Wo^T as f16
#pragma unroll
    for (int it = 0; it < 16; ++it) {
        int idx = tid + it * 512;
        int c = idx & 255, d = idx >> 8;
        woT[c * 40 + d] = (half_t)Wo[d * CC + c];
    }

    // exact softmax merge of 4 k-split partials: thread -> (r = tid>>3, d4 = (tid&7)*4)
    {
        const int r = tid >> 3, d4 = (tid & 7) * 4;
        const int gr = r0 + r;
        float mv[4];
        float M = -3.0e38f;
#pragma unroll
        for (int k = 0; k < KSPLIT; ++k) {
            mv[k] = pm[(size_t)k * NROW + gr];
            M = fmaxf(M, mv[k]);
        }
        float S = 0.f;
        f32x4 f = {0.f, 0.f, 0.f, 0.f};
#pragma unroll
        for (int k = 0; k < KSPLIT; ++k) {
            float wgt = fexp2(mv[k] - M);
            S += ps[(size_t)k * NROW + gr] * wgt;
            f32x4 p = *reinterpret_cast<const f32x4*>(pO + ((size_t)k * NROW + gr) * 32 + d4);
            f += p * wgt;
        }
        float inv = 1.0f / S;
#pragma unroll
        for (int i = 0; i < 4; ++i) feat_h[r * 40 + d4 + i] = (half_t)(f[i] * inv);
    }
    __syncthreads();

    // MFMA epilogue: O[r][c] = gamma*(feat@Wo + bo) + x  (validated R9 structure)
    const int w = tid >> 6, lane = tid & 63;
    const int q = lane & 15, g = lane >> 4;
    const float gam = gamma[0];
#pragma unroll
    for (int j = 0; j < 2; ++j) {
        const int ct = w * 2 + j;
        half8_t kfe = *reinterpret_cast<const half8_t*>(&woT[(ct * 16 + q) * 40 + g * 8]);
        float4 bb4 = *reinterpret_cast<const float4*>(bo + ct * 16 + g * 4);
#pragma unroll
        for (int rt = 0; rt < 4; ++rt) {
            half8_t qfe = *reinterpret_cast<const half8_t*>(&feat_h[(rt * 16 + q) * 40 + g * 8]);
            f32x4 z = {0.f, 0.f, 0.f, 0.f};
            f32x4 o = MFMA_QK(kfe, qfe, z);
            const size_t base = ((size_t)b * NN + q0 + rt * 16 + q) * CC + ct * 16 + g * 4;
            float4 xv = *reinterpret_cast<const float4*>(x + base);
            float4 ov;
            ov.x = gam * (o[0] + bb4.x) + xv.x;
            ov.y = gam * (o[1] + bb4.y) + xv.y;
            ov.z = gam * (o[2] + bb4.z) + xv.z;
            ov.w = gam * (o[3] + bb4.w) + xv.w;
            *reinterpret_cast<float4*>(out + base) = ov;
        }
    }
}

// ---------------- launch ----------------
extern "C" void kernel_launch(void* const* d_in, const int* in_sizes, int n_in,
                              void* d_out, int out_size, void* d_ws, size_t ws_size,
                              hipStream_t stream) {
    const float* x  = (const float*)d_in[0];
    const float* Wk = (const float*)d_in[1];
    const float* bk = (const float*)d_in[2];
    const float* Wq = (const float*)d_in[3];
    const float* bq = (const float*)d_in[4];
    const float* Wv = (const float*)d_in[5];
    const float* bv = (const float*)d_in[6];
    const float* Wo = (const float*)d_in[7];
    const float* bo = (const float*)d_in[8];
    const float* gamma = (const float*)d_in[9];
    float* out = (float*)d_out;

    half_t* k_ws = (half_t*)d_ws;
    half_t* q_ws = k_ws + (size_t)BB * NN * DD;
    half_t* vT3  = q_ws + (size_t)BB * NN * DD;
    float*  pm   = (float*)(vT3 + (size_t)BB * NN * DD);
    float*  ps   = pm + (size_t)KSPLIT * NROW;
    float*  pO   = ps + (size_t)KSPLIT * NROW;

    proj_kernel<<<256, 512, 0, stream>>>(x, Wk, bk, Wq, bq, Wv, bv, k_ws, q_ws, vT3);
    attn_partial<<<256, 512, 0, stream>>>(k_ws, q_ws, vT3, pm, ps, pO);
    attn_combine<<<256, 512, 0, stream>>>(pm, ps, pO, x, Wo, bo, gamma, out);
}

// Round 13
// 39.425 us; speedup vs baseline: 1.2502x; 1.2502x over previous
//
#include <hip/hip_runtime.h>
#include <hip/hip_bf16.h>
#include <hip/hip_fp16.h>

// Self-attention: B=4, H=W=64 (N=4096), C=256, D=32.
//   proj_kernel : MFMA GEMM, 64-row blocks (~2.5us). k,q row-major [B*N][32] f16
//                 (q pre-scaled by log2e); v tiled vT2[b][n/16][d][n%16].
//   attn_kernel : R10 structure (validated best): block = 64 q-rows, 512 threads =
//                 8 waves k-split (512 k each), swapped-operand MFMA, 1-deep register
//                 prefetch, defer-max softmax, padded combine, MFMA Wo-epilogue.
//                 NEW: amdgpu_waves_per_eu(1,2) pins allocator to <=2 waves/EU ->
//                 VGPR cap 256 (demand ~130) -> no scratch spills (R8 showed the
//                 allocator otherwise targets 64 VGPR and spills ~60 regs/thread).

#define BB 4
#define NN 4096
#define CC 256
#define DD 32
#define LOG2E 1.44269504088896340736f
#define THR2 11.0f

typedef _Float16 half_t;
typedef _Float16 half2_t __attribute__((ext_vector_type(2)));
typedef _Float16 half4_t __attribute__((ext_vector_type(4)));
typedef _Float16 half8_t __attribute__((ext_vector_type(8)));
typedef float f32x4 __attribute__((ext_vector_type(4)));

#define MFMA_QK(a, b, c) __builtin_amdgcn_mfma_f32_16x16x32_f16(a, b, c, 0, 0, 0)
#define MFMA_PV(a, b, c) __builtin_amdgcn_mfma_f32_16x16x16f16(a, b, c, 0, 0, 0)

static __device__ inline float fexp2(float x) {
#if __has_builtin(__builtin_amdgcn_exp2f)
    return __builtin_amdgcn_exp2f(x);
#else
    return exp2f(x);
#endif
}

// ---------------- Kernel 1: fused QKV projection (MFMA) ----------------
// grid 256 blocks x 512 threads (8 waves); block = 64 rows of x.
// XCD-pinned: batch = (bid&7)>>1, chunk = ((bid>>3)<<1)|(bid&1).
__global__ __launch_bounds__(512) void proj_kernel(
    const float* __restrict__ x,
    const float* __restrict__ Wk, const float* __restrict__ bk,
    const float* __restrict__ Wq, const float* __restrict__ bq,
    const float* __restrict__ Wv, const float* __restrict__ bv,
    half_t* __restrict__ k_ws, half_t* __restrict__ q_ws, half_t* __restrict__ vT2)
{
    __shared__ half_t xs16[64][264];  // x tile f16 (rows 16B-aligned)
    __shared__ half_t Wt[96][264];    // [Wk|Wq|Wv]^T : Wt[wcol][kdim]

    const int t = threadIdx.x;
    const int xcd = blockIdx.x & 7, slot = blockIdx.x >> 3;
    const int bb = xcd >> 1;                      // batch 0..3
    const int c64 = (slot << 1) | (xcd & 1);      // chunk 0..63
    const int row0 = bb * NN + c64 * 64;

    // stage x tile [64][256] fp32 -> f16
    const float4* x4 = reinterpret_cast<const float4*>(x) + (size_t)row0 * 64;
    for (int idx = t; idx < 64 * 64; idx += 512) {
        int r = idx >> 6, c4 = idx & 63;
        float4 v = x4[r * 64 + c4];
        half4_t h;
        h[0] = (half_t)v.x; h[1] = (half_t)v.y; h[2] = (half_t)v.z; h[3] = (half_t)v.w;
        *reinterpret_cast<half4_t*>(&xs16[r][c4 * 4]) = h;
    }

    // stage W^T (q columns pre-scaled by log2e)
    for (int idx = t; idx < 3072; idx += 512) {
        int cp = idx & 127;           // c-pair
        int rest = idx >> 7;          // 0..23
        int d4 = (rest & 7) * 4;
        int mat = rest >> 3;          // 0:k 1:q 2:v
        const float* Wm = (mat == 0) ? Wk : ((mat == 1) ? Wq : Wv);
        const float sc = (mat == 1) ? LOG2E : 1.0f;
        float4 w0 = *reinterpret_cast<const float4*>(Wm + (2 * cp) * DD + d4);
        float4 w1 = *reinterpret_cast<const float4*>(Wm + (2 * cp + 1) * DD + d4);
        int rbase = mat * 32 + d4;
        half2_t h;
        h[0] = (half_t)(w0.x * sc); h[1] = (half_t)(w1.x * sc);
        *reinterpret_cast<half2_t*>(&Wt[rbase + 0][2 * cp]) = h;
        h[0] = (half_t)(w0.y * sc); h[1] = (half_t)(w1.y * sc);
        *reinterpret_cast<half2_t*>(&Wt[rbase + 1][2 * cp]) = h;
        h[0] = (half_t)(w0.z * sc); h[1] = (half_t)(w1.z * sc);
        *reinterpret_cast<half2_t*>(&Wt[rbase + 2][2 * cp]) = h;
        h[0] = (half_t)(w0.w * sc); h[1] = (half_t)(w1.w * sc);
        *reinterpret_cast<half2_t*>(&Wt[rbase + 3][2 * cp]) = h;
    }
    __syncthreads();

    const int w = t >> 6, lane = t & 63;
    const int c = lane & 15, g = lane >> 4;
    const int rt = w >> 1;            // row tile 0..3
    const int ct0 = (w & 1) * 3;      // col tiles ct0..ct0+2

    f32x4 acc[3];
#pragma unroll
    for (int j = 0; j < 3; ++j) acc[j] = (f32x4){0.f, 0.f, 0.f, 0.f};

#pragma unroll
    for (int kk = 0; kk < 8; ++kk) {
        const int k0 = kk * 32 + g * 8;
        half8_t bfrag = *reinterpret_cast<const half8_t*>(&xs16[rt * 16 + c][k0]);
#pragma unroll
        for (int j = 0; j < 3; ++j) {
            half8_t afrag = *reinterpret_cast<const half8_t*>(&Wt[(ct0 + j) * 16 + c][k0]);
            acc[j] = MFMA_QK(afrag, bfrag, acc[j]);
        }
    }

    // store: lane holds C[xrow = rt*16+c][wcol = ct*16+4g+i]
    const int grow = row0 + rt * 16 + c;
#pragma unroll
    for (int j = 0; j < 3; ++j) {
        const int ct = ct0 + j;
        const int mat = ct >> 1;           // 0:k 1:q 2:v
        const float* bm = (mat == 0) ? bk : ((mat == 1) ? bq : bv);
        float4 bb4 = *reinterpret_cast<const float4*>(bm + (ct & 1) * 16 + g * 4);
        if (mat < 2) {
            const float bsc = (mat == 1) ? LOG2E : 1.0f;
            half_t* dst = (mat == 0) ? k_ws : q_ws;
            half4_t h;
            h[0] = (half_t)(acc[j][0] + bb4.x * bsc);
            h[1] = (half_t)(acc[j][1] + bb4.y * bsc);
            h[2] = (half_t)(acc[j][2] + bb4.z * bsc);
            h[3] = (half_t)(acc[j][3] + bb4.w * bsc);
            *reinterpret_cast<half4_t*>(dst + (size_t)grow * DD + (ct & 1) * 16 + g * 4) = h;
        } else {
            // vT2[(row0>>4)+rt][d][n%16], d = (ct&1)*16+g*4+i, n%16 = c
            const size_t tbase = ((size_t)(row0 >> 4) + rt) * 512;
            const int d0 = (ct & 1) * 16 + g * 4;
            vT2[tbase + (size_t)(d0 + 0) * 16 + c] = (half_t)(acc[j][0] + bb4.x);
            vT2[tbase + (size_t)(d0 + 1) * 16 + c] = (half_t)(acc[j][1] + bb4.y);
            vT2[tbase + (size_t)(d0 + 2) * 16 + c] = (half_t)(acc[j][2] + bb4.z);
            vT2[tbase + (size_t)(d0 + 3) * 16 + c] = (half_t)(acc[j][3] + bb4.w);
        }
    }
}

// ---------------- Kernel 2: flash attention + output projection ----------------
// grid 256 blocks x 512 threads (8 waves). Block = 64 q rows (4 tiles/wave).
// XCD-pinned: batch = (bid&7)>>1, qb = ((bid>>3)<<1)|(bid&1).
// Wave w: k in [w*512, (w+1)*512), 2 k-tiles of 16 per iter, 16 iters, 1-deep prefetch.
// waves_per_eu(1,2): VGPR cap 256 -> no spills (demand ~130).
__global__ __launch_bounds__(512)
__attribute__((amdgpu_waves_per_eu(1, 2))) void attn_kernel(
    const half_t* __restrict__ k_ws, const half_t* __restrict__ q_ws,
    const half_t* __restrict__ vT2,
    const float* __restrict__ x, const float* __restrict__ Wo,
    const float* __restrict__ bo, const float* __restrict__ gamma,
    float* __restrict__ out)
{
    __shared__ float acc_l[8][64][33];    // 67.6 KB, 33-pad -> conflict-free combine
    __shared__ float m_l[8][4][16];       // 2 KB
    __shared__ float s_l[8][4][16];       // 2 KB
    __shared__ half_t feat_h[64 * 40];    // 5 KB  feat f16, 40-halves rows
    __shared__ half_t woT[256 * 40];      // 20 KB Wo^T f16: woT[c*40+d]

    const int tid = threadIdx.x;
    const int w = tid >> 6, lane = tid & 63;
    const int q = lane & 15, g = lane >> 4;
    const int xcd = blockIdx.x & 7, slot = blockIdx.x >> 3;
    const int b = xcd >> 1;                       // batch 0..3 pinned to XCD pair
    const int qb = (slot << 1) | (xcd & 1);       // 0..63
    const int q0 = qb * 64;

    // stage Wo^T as f16 (coalesced reads; 8192 elements)
#pragma unroll
    for (int it = 0; it < 16; ++it) {
        int idx = tid + it * 512;
        int c = idx & 255, d = idx >> 8;
        woT[c * 40 + d] = (half_t)Wo[d * CC + c];
    }

    // Q fragments (B-operand of S^T = K*Q^T), pre-scaled by log2e
    half8_t qf[4];
#pragma unroll
    for (int t = 0; t < 4; ++t)
        qf[t] = *reinterpret_cast<const half8_t*>(
            q_ws + (size_t)(b * NN + q0 + t * 16 + q) * DD + g * 8);

    float m[4], ssum[4];
    f32x4 accd0[4], accd1[4];
#pragma unroll
    for (int t = 0; t < 4; ++t) {
        m[t] = -3.0e38f; ssum[t] = 0.f;
        accd0[t] = (f32x4){0.f, 0.f, 0.f, 0.f};
        accd1[t] = (f32x4){0.f, 0.f, 0.f, 0.f};
    }

    const half_t* kbase = k_ws + ((size_t)b * NN + q) * DD + g * 8;
    // vT2 tile = 512 halves [d(32)][n%16]; lane reads d={q,16+q}, n%16 = g*4..+3
    const half_t* vb = vT2 + (size_t)b * 256 * 512 + q * 16 + g * 4;

    const int ktbase = w * 32;

    // prologue: iteration 0's K and V fragments
    half8_t kc0 = *reinterpret_cast<const half8_t*>(kbase + (size_t)(ktbase + 0) * 16 * DD);
    half8_t kc1 = *reinterpret_cast<const half8_t*>(kbase + (size_t)(ktbase + 1) * 16 * DD);
    half4_t va0 = *reinterpret_cast<const half4_t*>(vb + (size_t)(ktbase + 0) * 512);
    half4_t va1 = *reinterpret_cast<const half4_t*>(vb + (size_t)(ktbase + 0) * 512 + 256);
    half4_t vc0 = *reinterpret_cast<const half4_t*>(vb + (size_t)(ktbase + 1) * 512);
    half4_t vc1 = *reinterpret_cast<const half4_t*>(vb + (size_t)(ktbase + 1) * 512 + 256);

    for (int it = 0; it < 16; ++it) {
        const int kt = ktbase + it * 2;
        const int ktn = (it < 15) ? (kt + 2) : kt;

        // prefetch next iteration's K and V fragments
        half8_t kn0 = *reinterpret_cast<const half8_t*>(kbase + (size_t)(ktn + 0) * 16 * DD);
        half8_t kn1 = *reinterpret_cast<const half8_t*>(kbase + (size_t)(ktn + 1) * 16 * DD);
        half4_t wa0 = *reinterpret_cast<const half4_t*>(vb + (size_t)(ktn + 0) * 512);
        half4_t wa1 = *reinterpret_cast<const half4_t*>(vb + (size_t)(ktn + 0) * 512 + 256);
        half4_t wc0 = *reinterpret_cast<const half4_t*>(vb + (size_t)(ktn + 1) * 512);
        half4_t wc1 = *reinterpret_cast<const half4_t*>(vb + (size_t)(ktn + 1) * 512 + 256);

        // QK^T: 8 MFMAs (4 q-tiles x 2 k-tiles) on resident K
        f32x4 z = {0.f, 0.f, 0.f, 0.f};
        f32x4 s0[4], s1[4];
#pragma unroll
        for (int t = 0; t < 4; ++t) {
            s0[t] = MFMA_QK(kc0, qf[t], z);
            s1[t] = MFMA_QK(kc1, qf[t], z);
        }

        float tmax[4];
        bool need = false;
#pragma unroll
        for (int t = 0; t < 4; ++t) {
            float t0 = fmaxf(fmaxf(s0[t][0], s0[t][1]), fmaxf(s0[t][2], s0[t][3]));
            float t1 = fmaxf(fmaxf(s1[t][0], s1[t][1]), fmaxf(s1[t][2], s1[t][3]));
            tmax[t] = fmaxf(t0, t1);
            need = need || (tmax[t] > m[t] + THR2);
        }

        // defer-max: rescale only when some lane/tile exceeds headroom
        if (__any(need)) {
#pragma unroll
            for (int t = 0; t < 4; ++t) {
                float rmax = tmax[t];
                rmax = fmaxf(rmax, __shfl_xor(rmax, 16));
                rmax = fmaxf(rmax, __shfl_xor(rmax, 32));
                float mn = fmaxf(m[t], rmax);
                float sc = fexp2(m[t] - mn);
                ssum[t] *= sc;
                accd0[t] *= sc;
                accd1[t] *= sc;
                m[t] = mn;
            }
        }

        // softmax (log2 domain) + PV per q-tile
#pragma unroll
        for (int t = 0; t < 4; ++t) {
            float p00 = fexp2(s0[t][0] - m[t]), p01 = fexp2(s0[t][1] - m[t]);
            float p02 = fexp2(s0[t][2] - m[t]), p03 = fexp2(s0[t][3] - m[t]);
            float p10 = fexp2(s1[t][0] - m[t]), p11 = fexp2(s1[t][1] - m[t]);
            float p12 = fexp2(s1[t][2] - m[t]), p13 = fexp2(s1[t][3] - m[t]);
            ssum[t] += ((p00 + p01) + (p02 + p03)) + ((p10 + p11) + (p12 + p13));

            half4_t pf0, pf1;
            pf0[0] = (half_t)p00; pf0[1] = (half_t)p01; pf0[2] = (half_t)p02; pf0[3] = (half_t)p03;
            pf1[0] = (half_t)p10; pf1[1] = (half_t)p11; pf1[2] = (half_t)p12; pf1[3] = (half_t)p13;

            accd0[t] = MFMA_PV(va0, pf0, accd0[t]);
            accd1[t] = MFMA_PV(va1, pf0, accd1[t]);
            accd0[t] = MFMA_PV(vc0, pf1, accd0[t]);
            accd1[t] = MFMA_PV(vc1, pf1, accd1[t]);
        }

        kc0 = kn0; kc1 = kn1;
        va0 = wa0; va1 = wa1; vc0 = wc0; vc1 = wc1;
    }

    // fold lane-local ssum to row sums
#pragma unroll
    for (int t = 0; t < 4; ++t) {
        ssum[t] += __shfl_xor(ssum[t], 16);
        ssum[t] += __shfl_xor(ssum[t], 32);
    }

    if (lane < 16) {
#pragma unroll
        for (int t = 0; t < 4; ++t) { m_l[w][t][lane] = m[t]; s_l[w][t][lane] = ssum[t]; }
    }
#pragma unroll
    for (int t = 0; t < 4; ++t)
#pragma unroll
        for (int i = 0; i < 4; ++i) {
            acc_l[w][lane][t * 8 + i] = accd0[t][i];
            acc_l[w][lane][t * 8 + 4 + i] = accd1[t][i];
        }
    __syncthreads();

    // waves 0..3 combine the 8 k-splits; wave w handles q-tile t=w.
    if (w < 4) {
        const int t = w;
        float M = m_l[0][t][q];
#pragma unroll
        for (int ww = 1; ww < 8; ++ww) M = fmaxf(M, m_l[ww][t][q]);
        float SS = 0.f;
        float f[8] = {0.f, 0.f, 0.f, 0.f, 0.f, 0.f, 0.f, 0.f};
#pragma unroll
        for (int ww = 0; ww < 8; ++ww) {
            float sc = fexp2(m_l[ww][t][q] - M);
            SS += s_l[ww][t][q] * sc;
#pragma unroll
            for (int i = 0; i < 8; ++i) f[i] += acc_l[ww][lane][t * 8 + i] * sc;
        }
        float inv = 1.0f / SS;
        half4_t h0, h1;
#pragma unroll
        for (int i = 0; i < 4; ++i) { h0[i] = (half_t)(f[i] * inv); h1[i] = (half_t)(f[4 + i] * inv); }
        *reinterpret_cast<half4_t*>(&feat_h[(t * 16 + q) * 40 + g * 4]) = h0;
        *reinterpret_cast<half4_t*>(&feat_h[(t * 16 + q) * 40 + 16 + g * 4]) = h1;
    }
    __syncthreads();

    // ---- MFMA epilogue: O[r][c] = gamma*(feat@Wo + bo) + x ----
    const float gam = gamma[0];
#pragma unroll
    for (int j = 0; j < 2; ++j) {
        const int ct = w * 2 + j;
        half8_t kfe = *reinterpret_cast<const half8_t*>(&woT[(ct * 16 + q) * 40 + g * 8]);
        float4 bb4 = *reinterpret_cast<const float4*>(bo + ct * 16 + g * 4);
#pragma unroll
        for (int rt = 0; rt < 4; ++rt) {
            half8_t qfe = *reinterpret_cast<const half8_t*>(&feat_h[(rt * 16 + q) * 40 + g * 8]);
            f32x4 z = {0.f, 0.f, 0.f, 0.f};
            f32x4 o = MFMA_QK(kfe, qfe, z);
            const size_t base = ((size_t)b * NN + q0 + rt * 16 + q) * CC + ct * 16 + g * 4;
            float4 xv = *reinterpret_cast<const float4*>(x + base);
            float4 ov;
            ov.x = gam * (o[0] + bb4.x) + xv.x;
            ov.y = gam * (o[1] + bb4.y) + xv.y;
            ov.z = gam * (o[2] + bb4.z) + xv.z;
            ov.w = gam * (o[3] + bb4.w) + xv.w;
            *reinterpret_cast<float4*>(out + base) = ov;
        }
    }
}

// ---------------- launch ----------------
extern "C" void kernel_launch(void* const* d_in, const int* in_sizes, int n_in,
                              void* d_out, int out_size, void* d_ws, size_t ws_size,
                              hipStream_t stream) {
    const float* x  = (const float*)d_in[0];
    const float* Wk = (const float*)d_in[1];
    const float* bk = (const float*)d_in[2];
    const float* Wq = (const float*)d_in[3];
    const float* bq = (const float*)d_in[4];
    const float* Wv = (const float*)d_in[5];
    const float* bv = (const float*)d_in[6];
    const float* Wo = (const float*)d_in[7];
    const float* bo = (const float*)d_in[8];
    const float* gamma = (const float*)d_in[9];
    float* out = (float*)d_out;

    half_t* k_ws  = (half_t*)d_ws;
    half_t* q_ws  = k_ws + (size_t)BB * NN * DD;
    half_t* vT2   = q_ws + (size_t)BB * NN * DD;

    proj_kernel<<<256, 512, 0, stream>>>(x, Wk, bk, Wq, bq, Wv, bv, k_ws, q_ws, vT2);
    attn_kernel<<<256, 512, 0, stream>>>(k_ws, q_ws, vT2, x, Wo, bo, gamma, out);
}